// Round 12
// baseline (291.488 us; speedup 1.0000x reference)
//
#include <hip/hip_runtime.h>
#include <stdint.h>

// Fused attention: qh=q@Wq^T+b, kh=k@Wk^T+b, vh=v@Wv^T+b,
// S=qh@kh^T/32 (causal+pad mask), P=softmax(S), out=P@vh.
// B=4, S=2048, M=H=1024. bf16 MFMA compute (threshold permits bf16).
//
// R14: pv single-writer via complementary pairing (289.5us).
// R15: cooperative score+pv fusion FAILED: hipLaunchCooperativeKernel does
//      not execute under the harness's graph capture (out stayed 0,
//      absmax == max|ref|). Grid-wide sync is off the table.
// R16: sync-free fusion instead: proj_v + score are INDEPENDENT (disjoint
//      in/out sets) and same block shape -> one kernel, union grid 1056
//      (w<544: score job, else proj_v job). Saves a kernel boundary
//      (~8-10us, R14 evidence) and lets the dispatcher absorb score's
//      32-job tail round. 136 & 544 are 0 mod 8 so all %8 XCD groupings
//      survive the 1D flattening. Bodies verbatim from R14.

typedef __attribute__((ext_vector_type(8))) short s8v;   // 8 x bf16 (4 VGPRs)
typedef __attribute__((ext_vector_type(4))) float f4v;   // MFMA accumulator

__device__ __forceinline__ unsigned short f2bf(float f) {
    union { float f; unsigned u; } v; v.f = f;
    unsigned u = v.u;
    u = u + 0x7fffu + ((u >> 16) & 1u);   // round-to-nearest-even
    return (unsigned short)(u >> 16);
}

// async global->LDS, 16B per lane. LDS dest = wave-uniform base + lane*16.
__device__ __forceinline__ void gld_lds16(const void* gptr, void* lptr) {
    __builtin_amdgcn_global_load_lds(
        (const __attribute__((address_space(1))) unsigned int*)(uintptr_t)gptr,
        (__attribute__((address_space(3))) unsigned int*)(unsigned int)(uintptr_t)lptr,
        16, 0, 0);
}

// ---------------- fp32 -> bf16 convert, 8 floats/thread; + l zero ----------------
// blocks: q 4096, k 4096, v 4096, wq 512, wk 512, wv 512, l 4  (total 13828)
__global__ __launch_bounds__(256) void convert_all(
    const float* __restrict__ q, const float* __restrict__ k, const float* __restrict__ v,
    const float* __restrict__ wq, const float* __restrict__ wk, const float* __restrict__ wv,
    unsigned short* __restrict__ qb, unsigned short* __restrict__ kb, unsigned short* __restrict__ vb,
    unsigned short* __restrict__ wqb, unsigned short* __restrict__ wkb, unsigned short* __restrict__ wvb,
    float* __restrict__ l)
{
    int b = blockIdx.x;
    if (b >= 13824) {                      // trailing 4 blocks: zero l (8192 floats)
        int li = (b - 13824) * 2048 + threadIdx.x * 8;
        float4 z = {0.f, 0.f, 0.f, 0.f};
        *(float4*)(l + li) = z;
        *(float4*)(l + li + 4) = z;
        return;
    }
    const float* src; unsigned short* dst; int blk;
    if (b < 4096)       { src = q;  dst = qb;  blk = b; }
    else if (b < 8192)  { src = k;  dst = kb;  blk = b - 4096; }
    else if (b < 12288) { src = v;  dst = vb;  blk = b - 8192; }
    else if (b < 12800) { src = wq; dst = wqb; blk = b - 12288; }
    else if (b < 13312) { src = wk; dst = wkb; blk = b - 12800; }
    else                { src = wv; dst = wvb; blk = b - 13312; }
    size_t idx = (size_t)blk * 2048 + (size_t)threadIdx.x * 8;
    float4 f0 = *(const float4*)(src + idx);
    float4 f1 = *(const float4*)(src + idx + 4);
    s8v o;
    o[0] = (short)f2bf(f0.x); o[1] = (short)f2bf(f0.y);
    o[2] = (short)f2bf(f0.z); o[3] = (short)f2bf(f0.w);
    o[4] = (short)f2bf(f1.x); o[5] = (short)f2bf(f1.y);
    o[6] = (short)f2bf(f1.z); o[7] = (short)f2bf(f1.w);
    *(s8v*)(dst + idx) = o;
}

// ---------------- shared GEMM core: C(128x128) = A(128xK) * Bt(128xK)^T ----------------
// A row-major (lda), Bt row-major (ldb); both K-contiguous. bf16 in, fp32 acc.
// 256 threads = 4 waves in 2x2; each wave: 64x64 via 4x4 mfma_f32_16x16x32_bf16.
// Double-buffered (As/Bs each hold 2 x 128x32 tiles), ONE barrier per k-tile.
__device__ __forceinline__ void gemm_tiles(
    const unsigned short* __restrict__ A, int lda,
    const unsigned short* __restrict__ Bt, int ldb,
    int m0, int n0, int kTiles,
    unsigned short* As, unsigned short* Bs,   // each 2*128*32 elements
    f4v acc[4][4])
{
    const int t    = threadIdx.x;
    const int lane = t & 63;
    const int wave = t >> 6;
    const int wm   = (wave >> 1) * 64;
    const int wn   = (wave & 1) * 64;
    const int l15  = lane & 15;
    const int quad = lane >> 4;

    // staging: tile = 128 rows x 32 bf16 (64B/row) = 512 chunks of 16B; 2 chunks/thread
    const int c0 = t, c1 = t + 256;
    unsigned short* As0 = As + (c0 & ~63) * 8;   // wave-uniform LDS base
    unsigned short* As1 = As + (c1 & ~63) * 8;
    unsigned short* Bs0 = Bs + (c0 & ~63) * 8;
    unsigned short* Bs1 = Bs + (c1 & ~63) * 8;
    const unsigned short* Ag0 = A  + (size_t)(m0 + (c0 >> 2)) * lda + (c0 & 3) * 8;
    const unsigned short* Ag1 = A  + (size_t)(m0 + (c1 >> 2)) * lda + (c1 & 3) * 8;
    const unsigned short* Bg0 = Bt + (size_t)(n0 + (c0 >> 2)) * ldb + (c0 & 3) * 8;
    const unsigned short* Bg1 = Bt + (size_t)(n0 + (c1 >> 2)) * ldb + (c1 & 3) * 8;

    const unsigned short* a_base = As + quad * 8;
    const unsigned short* b_base = Bs + quad * 8;

    // prologue: stage k-tile 0 into buffer parity 0
    gld_lds16(Ag0, As0);
    gld_lds16(Ag1, As1);
    gld_lds16(Bg0, Bs0);
    gld_lds16(Bg1, Bs1);

    for (int kt = 0; kt < kTiles; ++kt) {
        __syncthreads();   // s_waitcnt vmcnt(0) drains buf[kt&1] loads + barrier
        Ag0 += 32; Ag1 += 32; Bg0 += 32; Bg1 += 32;
        if (kt + 1 < kTiles) {
            const int nb = ((kt + 1) & 1) * 4096;   // elements: 128*32
            gld_lds16(Ag0, As0 + nb);
            gld_lds16(Ag1, As1 + nb);
            gld_lds16(Bg0, Bs0 + nb);
            gld_lds16(Bg1, Bs1 + nb);
        }
        const int cb = (kt & 1) * 4096;
        s8v af[4], bf[4];
        #pragma unroll
        for (int i = 0; i < 4; ++i)   // A frag: A[m=l15][k=quad*8+j]
            af[i] = *(const s8v*)(a_base + cb + (wm + i * 16 + l15) * 32);
        #pragma unroll
        for (int j = 0; j < 4; ++j)   // B frag: Bt[n=l15][k=quad*8+j]
            bf[j] = *(const s8v*)(b_base + cb + (wn + j * 16 + l15) * 32);
        #pragma unroll
        for (int i = 0; i < 4; ++i)
            #pragma unroll
            for (int j = 0; j < 4; ++j)
                acc[i][j] = __builtin_amdgcn_mfma_f32_16x16x32_bf16(af[i], bf[j], acc[i][j], 0, 0, 0);
    }
}

#define ACC_INIT  f4v acc[4][4]; { f4v z = {0.f,0.f,0.f,0.f}; \
    _Pragma("unroll") for (int i = 0; i < 4; ++i) \
    _Pragma("unroll") for (int j = 0; j < 4; ++j) acc[i][j] = z; }

#define LANE_VARS \
    const int lane = threadIdx.x & 63; const int wave = threadIdx.x >> 6; \
    const int wm = (wave >> 1) * 64;  const int wn = (wave & 1) * 64; \
    const int l15 = lane & 15;        const int quad = lane >> 4;

// ---------------- Q/K projections: Y = X @ W^T + b ----------------
// 1D grid 256: w = (mx<<3) | (z<<2) | ny. XCD = w%8 = (z,ny) -> all 32 blocks
// sharing one W 256-col panel (512 KB) land on the same XCD L2.
// 256x256 tile, BK=64, 512 thr, 8 waves 2Mx4N; acc[8][4]; 3-barrier K-loop.
__global__ __launch_bounds__(512, 2) void proj_qk(
    const unsigned short* __restrict__ qb, const unsigned short* __restrict__ wqb,
    const float* __restrict__ bq, unsigned short* __restrict__ QH,
    const unsigned short* __restrict__ kb, const unsigned short* __restrict__ wkb,
    const float* __restrict__ bk, unsigned short* __restrict__ KH)
{
    const int w_ = blockIdx.x;          // 0..255
    const int yz = w_ & 7;
    const int ny = yz & 3;
    const int z  = yz >> 2;
    const int mx = w_ >> 3;             // 0..31
    const unsigned short* X; const unsigned short* W; const float* bias; unsigned short* Y;
    if (z == 0) { X = qb; W = wqb; bias = bq; Y = QH; }
    else        { X = kb; W = wkb; bias = bk; Y = KH; }

    __shared__ __align__(16) unsigned short As[2 * 256 * 64];   // 64 KiB
    __shared__ __align__(16) unsigned short Bs[2 * 256 * 64];   // 64 KiB

    const int t    = threadIdx.x;
    const int lane = t & 63;
    const int w    = t >> 6;
    const int wm   = (w >> 2) * 128;     // wave m-origin in tile
    const int wn   = (w & 3) * 64;       // wave n-origin in tile
    const int l15  = lane & 15;
    const int quad = lane >> 4;
    const int m0   = mx * 256;
    const int n0   = ny * 256;
    enum { KT = 16 };                    // 1024 / 64

    // staging: thread t owns chunks t and t+512 of each 128x64 half-tile.
    // chunk c: row = c>>3 (chunk1: +64), seg = c&7; global col-seg = seg^(row&7).
    const int r0 = t >> 3;                       // 0..63
    const int sw = (t & 7) ^ (r0 & 7);           // same for both chunks
    const unsigned short* gA = X + (size_t)(m0 + r0) * 1024 + sw * 8;
    const unsigned short* gB = W + (size_t)(n0 + r0) * 1024 + sw * 8;
    unsigned short* lA = As + (t & ~63) * 8;     // wave-uniform base
    unsigned short* lB = Bs + (t & ~63) * 8;

#define PSTAGE_A(b, h, kt) { \
    gld_lds16(gA + (size_t)(h) * 131072 + (kt) * 64,         lA + (b) * 16384 + (h) * 8192); \
    gld_lds16(gA + (size_t)(h) * 131072 + 65536 + (kt) * 64, lA + (b) * 16384 + (h) * 8192 + 4096); }
#define PSTAGE_B(b, h, kt) { \
    gld_lds16(gB + (size_t)(h) * 131072 + (kt) * 64,         lB + (b) * 16384 + (h) * 8192); \
    gld_lds16(gB + (size_t)(h) * 131072 + 65536 + (kt) * 64, lB + (b) * 16384 + (h) * 8192 + 4096); }

    // frag read offsets (elements); row&7 == l15&7 for all frag rows
    const int aoff = (wm + l15) * 64;
    const int boff = (wn + l15) * 64;
    const int seg0 = ((quad    ) ^ (l15 & 7)) * 8;   // k-slice 0 (k 0..31)
    const int seg1 = ((quad | 4) ^ (l15 & 7)) * 8;   // k-slice 1 (k 32..63)

    f4v acc[8][4];
    { f4v zz = {0.f, 0.f, 0.f, 0.f};
      #pragma unroll
      for (int i = 0; i < 8; ++i)
        #pragma unroll
        for (int j = 0; j < 4; ++j) acc[i][j] = zz; }
    s8v a[8], b0[4], b1[4];

    // prologue: T0 fully + T1's {Bh0, Ah0} (the late-slot halves), 12 loads.
    PSTAGE_A(0, 0, 0); PSTAGE_A(0, 1, 0); PSTAGE_B(0, 0, 0); PSTAGE_B(0, 1, 0);
    PSTAGE_B(1, 0, 1); PSTAGE_A(1, 0, 1);
    asm volatile("s_waitcnt vmcnt(4)" ::: "memory");
    __builtin_amdgcn_s_barrier();

    for (int kt = 0; kt < KT; ++kt) {
        const int p  = kt & 1;
        const int np = p ^ 1;
        const unsigned short* Ar = As + p * 16384 + aoff;
        const unsigned short* Br = Bs + p * 16384 + boff;

        // S1: issue ALL lo-cluster reads: a_lo(8), b0(4), b1(4).
        #pragma unroll
        for (int i = 0; i < 4; ++i) {
            a[i * 2]     = *(const s8v*)(Ar + i * 1024 + seg0);
            a[i * 2 + 1] = *(const s8v*)(Ar + i * 1024 + seg1);
        }
        #pragma unroll
        for (int j = 0; j < 2; ++j) {
            b0[j * 2]     = *(const s8v*)(Br + j * 1024 + seg0);
            b0[j * 2 + 1] = *(const s8v*)(Br + j * 1024 + seg1);
        }
        #pragma unroll
        for (int j = 0; j < 2; ++j) {
            b1[j * 2]     = *(const s8v*)(Br + 2048 + j * 1024 + seg0);
            b1[j * 2 + 1] = *(const s8v*)(Br + 2048 + j * 1024 + seg1);
        }
        if (kt + 1 < KT) PSTAGE_A(np, 1, kt + 1);   // S2
        __builtin_amdgcn_s_setprio(1);
        #pragma unroll
        for (int i = 0; i < 4; ++i)                  // S3: MFMA (m-lo, n-lo)
            #pragma unroll
            for (int j = 0; j < 2; ++j) {
                acc[i][j] = __builtin_amdgcn_mfma_f32_16x16x32_bf16(a[i*2],   b0[j*2],   acc[i][j], 0, 0, 0);
                acc[i][j] = __builtin_amdgcn_mfma_f32_16x16x32_bf16(a[i*2+1], b0[j*2+1], acc[i][j], 0, 0, 0);
            }
        __builtin_amdgcn_s_setprio(0);
        if (kt + 1 < KT) PSTAGE_B(np, 1, kt + 1);   // S4
        __builtin_amdgcn_s_setprio(1);
        #pragma unroll
        for (int i = 0; i < 4; ++i)                  // S5: MFMA (m-lo, n-hi)
            #pragma unroll
            for (int j = 0; j < 2; ++j) {
                acc[i][2+j] = __builtin_amdgcn_mfma_f32_16x16x32_bf16(a[i*2],   b1[j*2],   acc[i][2+j], 0, 0, 0);
                acc[i][2+j] = __builtin_amdgcn_mfma_f32_16x16x32_bf16(a[i*2+1], b1[j*2+1], acc[i][2+j], 0, 0, 0);
            }
        __builtin_amdgcn_s_setprio(0);
        // S6: a_hi reads (a_lo regs dead after S5)
        #pragma unroll
        for (int i = 0; i < 4; ++i) {
            a[i * 2]     = *(const s8v*)(Ar + 4096 + i * 1024 + seg0);
            a[i * 2 + 1] = *(const s8v*)(Ar + 4096 + i * 1024 + seg1);
        }
        __builtin_amdgcn_s_barrier();               // [E] all waves consumed a_lo,b0,b1
        if (kt + 2 < KT) PSTAGE_B(p, 0, kt + 2);    // S7: B parity-p dead after E
        __builtin_amdgcn_s_setprio(1);
        #pragma unroll
        for (int i = 0; i < 4; ++i)                  // S8: MFMA (m-hi, n-hi)
            #pragma unroll
            for (int j = 0; j < 2; ++j) {
                acc[4+i][2+j] = __builtin_amdgcn_mfma_f32_16x16x32_bf16(a[i*2],   b1[j*2],   acc[4+i][2+j], 0, 0, 0);
                acc[4+i][2+j] = __builtin_amdgcn_mfma_f32_16x16x32_bf16(a[i*2+1], b1[j*2+1], acc[4+i][2+j], 0, 0, 0);
            }
        __builtin_amdgcn_s_setprio(0);
        __builtin_amdgcn_s_barrier();               // [F] all waves consumed a_hi
        if (kt + 2 < KT) PSTAGE_A(p, 0, kt + 2);    // S9: A parity-p dead after F
        __builtin_amdgcn_s_setprio(1);
        #pragma unroll
        for (int i = 0; i < 4; ++i)                  // S10: MFMA (m-hi, n-lo), reg-only
            #pragma unroll
            for (int j = 0; j < 2; ++j) {
                acc[4+i][j] = __builtin_amdgcn_mfma_f32_16x16x32_bf16(a[i*2],   b0[j*2],   acc[4+i][j], 0, 0, 0);
                acc[4+i][j] = __builtin_amdgcn_mfma_f32_16x16x32_bf16(a[i*2+1], b0[j*2+1], acc[4+i][j], 0, 0, 0);
            }
        __builtin_amdgcn_s_setprio(0);
        // S11: counted drain; leaves S7+S9 (4 loads) in flight.
        if (kt + 2 < KT) { asm volatile("s_waitcnt vmcnt(4)" ::: "memory"); }
        else             { asm volatile("s_waitcnt vmcnt(0)" ::: "memory"); }
        __builtin_amdgcn_s_barrier();               // [G] tile end
    }
#undef PSTAGE_A
#undef PSTAGE_B

    // epilogue: C/D frag mapping row = quad*4+r, col = l15
    #pragma unroll
    for (int ig = 0; ig < 8; ++ig) {
        int row = m0 + wm + ig * 16 + quad * 4;
        #pragma unroll
        for (int jg = 0; jg < 4; ++jg) {
            int col = n0 + wn + jg * 16 + l15;
            float bvv = bias[col];
            #pragma unroll
            for (int r = 0; r < 4; ++r)
                Y[(size_t)(row + r) * 1024 + col] = f2bf(acc[ig][jg][r] + bvv);
        }
    }
}

// ---------------- fused score + V-projection (independent jobs, union grid) ----------------
// Grid 1056 x 256 thr:
//   w < 544 : score job s=w.  b = s/136, u = s%136, tq = (u%8)*17 + u/8
//             (bijective tri swizzle; 136%8==0 so XCD grouping survives).
//             S = QH@KH^T/32, P~ = exp(S) masked, rowsum -> atomicAdd l.
//   w >= 544: proj_v job j=w-544.  VH^T tile (m0=(j>>3)*128, n0=(j&7)*128);
//             (544%8==0 -> j%8 == w%8, Wv-panel XCD grouping survives).
// No data overlap between the two job families -> no sync needed.
__global__ __launch_bounds__(256) void score_projv(
    const unsigned short* __restrict__ QH, const unsigned short* __restrict__ KH,
    const int* __restrict__ mask, unsigned short* __restrict__ P,
    float* __restrict__ lsum,
    const unsigned short* __restrict__ vb, const unsigned short* __restrict__ wvb,
    const float* __restrict__ bv, unsigned short* __restrict__ VHT)
{
    __shared__ __align__(16) unsigned short As[2 * 128 * 32];
    __shared__ __align__(16) unsigned short Bs[2 * 128 * 32];
    const int w_ = blockIdx.x;           // 0..1055

    if (w_ < 544) {
        // ---- score job ----
        const int b = w_ / 136;
        const int u = w_ - b * 136;          // 0..135
        int tq = (u & 7) * 17 + (u >> 3);    // XCD-grouped tri index
        int qt = 0;
        while ((qt + 1) * (qt + 2) / 2 <= tq) ++qt;   // scalar, wave-uniform
        const int kt = tq - qt * (qt + 1) / 2;

        const unsigned short* A  = QH + (size_t)b * 2048 * 1024;
        const unsigned short* Bt = KH + (size_t)b * 2048 * 1024;
        unsigned short* Pb = P + (size_t)b * 2048 * 2048;
        float* lb = lsum + b * 2048;
        const int* mb = mask + b * 2048;
        const int m0 = qt * 128, n0 = kt * 128;
        ACC_INIT;
        gemm_tiles(A, 1024, Bt, 1024, m0, n0, 32, As, Bs, acc);
        LANE_VARS;
        float rs[4][4];
        #pragma unroll
        for (int i = 0; i < 4; ++i)
            #pragma unroll
            for (int r = 0; r < 4; ++r) rs[i][r] = 0.f;
        #pragma unroll
        for (int i = 0; i < 4; ++i) {
            int qbase = m0 + wm + i * 16 + quad * 4;
            #pragma unroll
            for (int j = 0; j < 4; ++j) {
                int kg = n0 + wn + j * 16 + l15;
                int mv = mb[kg];
                #pragma unroll
                for (int r = 0; r < 4; ++r) {
                    float sc = acc[i][j][r] * 0.03125f;   // 1/sqrt(1024)
                    float p = (mv && (kg <= qbase + r)) ? __expf(sc) : 0.f;
                    Pb[(size_t)(qbase + r) * 2048 + kg] = f2bf(p);
                    rs[i][r] += p;
                }
            }
        }
        // reduce rowsums across the 16 lanes (l15) sharing each (quad, reg) row
        #pragma unroll
        for (int i = 0; i < 4; ++i)
            #pragma unroll
            for (int r = 0; r < 4; ++r) {
                float v_ = rs[i][r];
                v_ += __shfl_xor(v_, 1);
                v_ += __shfl_xor(v_, 2);
                v_ += __shfl_xor(v_, 4);
                v_ += __shfl_xor(v_, 8);
                if (l15 == 0)
                    atomicAdd(&lb[m0 + wm + i * 16 + quad * 4 + r], v_);
            }
    } else {
        // ---- proj_v job: VH^T = (v @ Wv^T + b)^T ----
        const int j_ = w_ - 544;             // 0..511
        const int m0 = (j_ >> 3) * 128;
        const int n0 = (j_ & 7) * 128;
        ACC_INIT;
        gemm_tiles(vb, 1024, wvb, 1024, m0, n0, 32, As, Bs, acc);
        LANE_VARS;
        #pragma unroll
        for (int i = 0; i < 4; ++i) {
            int row = m0 + wm + i * 16 + quad * 4;   // C/D: row = quad*4+reg, col = l15
            int bb = row >> 11;                      // batch (rows 4-aligned within batch)
            int s  = row & 2047;
            #pragma unroll
            for (int j = 0; j < 4; ++j) {
                int col = n0 + wn + j * 16 + l15;
                float bvv = bv[col];
                ushort4 o = make_ushort4(f2bf(acc[i][j][0] + bvv), f2bf(acc[i][j][1] + bvv),
                                         f2bf(acc[i][j][2] + bvv), f2bf(acc[i][j][3] + bvv));
                *(ushort4*)(VHT + (size_t)bb * (1024 * 2048) + (size_t)col * 2048 + s) = o;
            }
        }
    }
}

// ---------------- PV, single-writer, complementary-pair balanced ----------------
// jobs = (b, qt, nt), kcount = 4*(qt+1) (full causal K; no split, no Part).
// 1D grid 512 (2 blocks/CU, all resident): w<256 -> qt = 15 - j (heavy),
// w>=256 -> qt = j (light); w and w+256 share a CU under round-robin dispatch
// -> per-CU work = 4(16-j) + 4(j+1) = 68 k-tiles, exactly balanced.
// XCD = w&7 = nt (V-panel L2 locality). 1/l folded into the store.
__global__ __launch_bounds__(256) void pv_kernel(
    const unsigned short* __restrict__ P, const unsigned short* __restrict__ VHT,
    const float* __restrict__ lsum, float* __restrict__ Out)
{
    const int w_   = blockIdx.x;         // 0..511
    const int nt   = w_ & 7;
    const int u    = w_ >> 3;            // 0..63
    const int half = u >> 5;             // 0: heavy half, 1: light half
    const int i_   = u & 31;
    const int b    = i_ >> 3;
    const int j_   = i_ & 7;
    const int qt   = half ? j_ : 15 - j_;
    const int kcount = 4 * (qt + 1);     // k-tiles of 32 -> cols 0..128*(qt+1)

    __shared__ __align__(16) unsigned short As[2 * 128 * 32];
    __shared__ __align__(16) unsigned short Bs[2 * 128 * 32];
    const unsigned short* A  = P   + (size_t)b * 2048 * 2048;
    const unsigned short* Bt = VHT + (size_t)b * 1024 * 2048;
    const float* lb = lsum + b * 2048;
    const int m0 = qt * 128, n0 = nt * 128;
    ACC_INIT;
    gemm_tiles(A, 2048, Bt, 2048, m0, n0, kcount, As, Bs, acc);
    LANE_VARS;
    float* dst = Out + (size_t)b * 2048 * 1024;
    #pragma unroll
    for (int i = 0; i < 4; ++i) {
        int q0 = m0 + wm + i * 16 + quad * 4;
        float inv[4];
        #pragma unroll
        for (int r = 0; r < 4; ++r) inv[r] = 1.0f / lb[q0 + r];
        #pragma unroll
        for (int j = 0; j < 4; ++j) {
            int h = n0 + wn + j * 16 + l15;
            #pragma unroll
            for (int r = 0; r < 4; ++r)
                dst[(size_t)(q0 + r) * 1024 + h] = acc[i][j][r] * inv[r];
        }
    }
}

extern "C" void kernel_launch(void* const* d_in, const int* in_sizes, int n_in,
                              void* d_out, int out_size, void* d_ws, size_t ws_size,
                              hipStream_t stream)
{
    const float* q    = (const float*)d_in[0];
    const float* k    = (const float*)d_in[1];
    const float* v    = (const float*)d_in[2];
    const int*   mask = (const int*)d_in[3];
    const float* Wq   = (const float*)d_in[4];
    const float* bq   = (const float*)d_in[5];
    const float* Wk   = (const float*)d_in[6];
    const float* bk   = (const float*)d_in[7];
    const float* Wv   = (const float*)d_in[8];
    const float* bv   = (const float*)d_in[9];
    float* out = (float*)d_out;

    // workspace carve (all sizes 256B-aligned); total ~124 MB
    char* ws = (char*)d_ws;
    size_t off = 0;
    auto take = [&](size_t bytes) { char* p = ws + off; off += (bytes + 255) & ~(size_t)255; return p; };
    unsigned short* qb  = (unsigned short*)take(8192ull * 1024 * 2);
    unsigned short* kb  = (unsigned short*)take(8192ull * 1024 * 2);
    unsigned short* vb  = (unsigned short*)take(8192ull * 1024 * 2);
    unsigned short* wqb = (unsigned short*)take(1024ull * 1024 * 2);
    unsigned short* wkb = (unsigned short*)take(1024ull * 1024 * 2);
    unsigned short* wvb = (unsigned short*)take(1024ull * 1024 * 2);
    unsigned short* QH  = (unsigned short*)take(8192ull * 1024 * 2);
    unsigned short* KH  = (unsigned short*)take(8192ull * 1024 * 2);
    unsigned short* VHT = (unsigned short*)take(8192ull * 1024 * 2);  // (B,1024,2048)
    unsigned short* P   = (unsigned short*)take(4ull * 2048 * 2048 * 2);
    float*          l   = (float*)take(4ull * 2048 * 4);

    convert_all<<<13828, 256, 0, stream>>>(q, k, v, Wq, Wk, Wv,
                                           qb, kb, vb, wqb, wkb, wvb, l);
    proj_qk<<<256, 512, 0, stream>>>(qb, wqb, bq, QH,
                                     kb, wkb, bk, KH);
    score_projv<<<1056, 256, 0, stream>>>(QH, KH, mask, P, l,
                                          vb, wvb, bv, VHT);
    pv_kernel<<<512, 256, 0, stream>>>(P, VHT, l, out);
}